// Round 21
// baseline (105.665 us; speedup 1.0000x reference)
//
#include <hip/hip_runtime.h>
#include <math.h>

#define DEV __device__ __forceinline__

typedef __attribute__((ext_vector_type(8))) short bf16x8;
typedef __attribute__((ext_vector_type(4))) float f32x4;
typedef __attribute__((ext_vector_type(4))) unsigned int u32x4;

typedef __attribute__((address_space(3))) unsigned int lds_u32;
typedef const __attribute__((address_space(1))) unsigned int glb_u32;

// async global->LDS, 16B per lane; lds dest = wave-uniform base + lane*16
DEV void gload16(const unsigned short* g, unsigned short* l) {
  __builtin_amdgcn_global_load_lds((glb_u32*)g, (lds_u32*)l, 16, 0, 0);
}

// LDS vector read at precomputed byte offset
DEV bf16x8 lds_read8(const unsigned short* base, unsigned int byteoff) {
  return *reinterpret_cast<const bf16x8*>(
      reinterpret_cast<const char*>(base) + byteoff);
}

// native v_exp_f32 (2^x), 1 instruction
DEV float fexp2(float x) { return __builtin_amdgcn_exp2f(x); }

// ---------- bf16 helpers ----------
DEV unsigned short f2bf(float f) {
  union { float f; unsigned int u; } v; v.f = f;
  unsigned int u = v.u;
  unsigned int r = (u + 0x7fffu + ((u >> 16) & 1u)) >> 16;
  return (unsigned short)r;
}
DEV float bf2f(unsigned short h) {
  union { unsigned int u; float f; } v; v.u = ((unsigned int)h) << 16;
  return v.f;
}
DEV unsigned int cvtpk_bf16(float lo, float hi) {
  unsigned int r;
  asm("v_cvt_pk_bf16_f32 %0, %1, %2" : "=v"(r) : "v"(lo), "v"(hi));
  return r;
}

// ---------- fp32 -> bf16 convert x3 + RoPE cos/sin table build, one launch ----------
__global__ void cvt3_f32_bf16(const float* __restrict__ ina,
                              unsigned short* __restrict__ outa, int n4a,
                              const float* __restrict__ inb,
                              unsigned short* __restrict__ outb, int n4b,
                              const float* __restrict__ inc,
                              unsigned short* __restrict__ outc, int n4c,
                              const int* __restrict__ pos,
                              float2* __restrict__ tab) {
  int stride = gridDim.x * blockDim.x;
  int total = n4a + n4b + n4c;
  int totalt = total + 2048 * 32;
  for (int i = blockIdx.x * blockDim.x + threadIdx.x; i < totalt; i += stride) {
    if (i < total) {
      const float* src;
      unsigned short* dst;
      int j = i;
      if (j < n4a) {
        src = ina; dst = outa;
      } else if ((j -= n4a) < n4b) {
        src = inb; dst = outb;
      } else {
        j -= n4b; src = inc; dst = outc;
      }
      float4 f = reinterpret_cast<const float4*>(src)[j];
      ushort4 o;
      o.x = f2bf(f.x); o.y = f2bf(f.y); o.z = f2bf(f.z); o.w = f2bf(f.w);
      reinterpret_cast<ushort4*>(dst)[j] = o;
    } else {
      int j2 = i - total;           // [0, 65536)
      int s = j2 >> 5, p = j2 & 31;
      float inv = __expf(-(float)p * (9.210340371976184f / 32.0f));
      float ang = (float)pos[s] * inv;
      tab[j2] = make_float2(cosf(ang), sinf(ang));
    }
  }
}

// ================= 256x256 8-phase GEMM for QKV, fused RoPE epilogue =================
// q,k output columns (brow0<2048) are rotated in-register using the cos/sin table:
// partner value via __shfl_xor(v,1) (adjacent cols live in fr^1), q scaled by
// 0.125*log2(e). v columns written plain.
__global__ __launch_bounds__(512, 2) void gemm8_qkv(const unsigned short* __restrict__ A,
                                                    const unsigned short* __restrict__ B,
                                                    unsigned short* __restrict__ C,
                                                    const float2* __restrict__ tab) {
  constexpr int K = 1024;
  constexpr int NK = 16;  // K / 64
  __shared__ unsigned short Ls[2][32768];  // per buf: A shorts [0,16384), B [16384,32768)

  const int tid = threadIdx.x;
  const int lane = tid & 63, wid = tid >> 6;
  const int wm = (wid >> 2) * 128;
  const int wn = (wid & 3) * 64;
  const int fr = lane & 15, kq = lane >> 4;

  int bid = blockIdx.x;
  int swz = (bid & 7) * 24 + (bid >> 3);
  int tm = swz & 15, tn = swz >> 4;  // 16 x 12
  const int arow0 = tm * 256, brow0 = tn * 256;

  const int subrow = lane >> 3;
  const int scol = ((lane & 7) ^ subrow) * 8;
  const unsigned short* aSrc = A + (size_t)(arow0 + wid * 8 + subrow) * K + scol;
  const unsigned short* bSrc = B + (size_t)(brow0 + wid * 8 + subrow) * K + scol;

  unsigned aoff[2], boff[2];
#pragma unroll
  for (int ks = 0; ks < 2; ks++) {
    unsigned x = ((unsigned)((ks * 4 + kq) ^ (fr & 7))) * 16;
    aoff[ks] = (unsigned)((wm + fr) * 128) + x;
    boff[ks] = 32768u + (unsigned)((wn + fr) * 128) + x;
  }

  f32x4 acc[8][4] = {};

#define STAGE_A8(BUF, H, T)                                                  \
  {                                                                          \
    gload16(aSrc + (size_t)((H) * 128) * K + (T) * 64,                       \
            &Ls[BUF][((H) * 128 + wid * 8) * 64]);                           \
    gload16(aSrc + (size_t)((H) * 128 + 64) * K + (T) * 64,                  \
            &Ls[BUF][((H) * 128 + 64 + wid * 8) * 64]);                      \
  }
#define STAGE_B8(BUF, H, T)                                                  \
  {                                                                          \
    gload16(bSrc + (size_t)((H) * 128) * K + (T) * 64,                       \
            &Ls[BUF][16384 + ((H) * 128 + wid * 8) * 64]);                   \
    gload16(bSrc + (size_t)((H) * 128 + 64) * K + (T) * 64,                  \
            &Ls[BUF][16384 + ((H) * 128 + 64 + wid * 8) * 64]);              \
  }

  STAGE_A8(0, 0, 0) STAGE_A8(0, 1, 0)
  STAGE_B8(0, 0, 0) STAGE_B8(0, 1, 0)
  STAGE_B8(1, 0, 1) STAGE_B8(1, 1, 1)
  asm volatile("s_waitcnt vmcnt(4)" ::: "memory");
  __builtin_amdgcn_s_barrier();

#define PHASE8(BUF, P, DO_STAGE)                                              \
  {                                                                           \
    bf16x8 af[2][2];                                                          \
    _Pragma("unroll") for (int mm = 0; mm < 2; mm++)                          \
      _Pragma("unroll") for (int ks = 0; ks < 2; ks++)                        \
        af[mm][ks] = lds_read8(Ls[BUF], aoff[ks] + ((P) * 2 + mm) * 2048);    \
    DO_STAGE                                                                  \
    __builtin_amdgcn_s_setprio(1);                                            \
    _Pragma("unroll") for (int mm = 0; mm < 2; mm++)                          \
      _Pragma("unroll") for (int j = 0; j < 4; j++)                           \
        _Pragma("unroll") for (int ks = 0; ks < 2; ks++)                      \
          acc[(P) * 2 + mm][j] = __builtin_amdgcn_mfma_f32_16x16x32_bf16(     \
              af[mm][ks], bq[j][ks], acc[(P) * 2 + mm][j], 0, 0, 0);          \
    __builtin_amdgcn_s_setprio(0);                                            \
  }

#define TILE8(T, BUF)                                                          \
  {                                                                            \
    bf16x8 bq[4][2];                                                           \
    _Pragma("unroll") for (int j = 0; j < 4; j++)                              \
      _Pragma("unroll") for (int ks = 0; ks < 2; ks++)                         \
        bq[j][ks] = lds_read8(Ls[BUF], boff[ks] + j * 2048);                   \
    PHASE8(BUF, 0, {                                                           \
      if ((T) + 1 < NK) { STAGE_A8(BUF ^ 1, 0, (T) + 1) STAGE_A8(BUF ^ 1, 1, (T) + 1) } \
    })                                                                         \
    __builtin_amdgcn_s_barrier();                                              \
    PHASE8(BUF, 1, { if ((T) + 2 < NK) STAGE_B8(BUF, 0, (T) + 2) })            \
    __builtin_amdgcn_s_barrier();                                              \
    PHASE8(BUF, 2, { if ((T) + 2 < NK) STAGE_B8(BUF, 1, (T) + 2) })            \
    __builtin_amdgcn_s_barrier();                                              \
    PHASE8(BUF, 3, {})                                                         \
    if ((T) + 2 < NK) {                                                        \
      asm volatile("s_waitcnt vmcnt(4)" ::: "memory");                         \
    } else {                                                                   \
      asm volatile("s_waitcnt vmcnt(0)" ::: "memory");                         \
    }                                                                          \
    __builtin_amdgcn_s_barrier();                                              \
    __builtin_amdgcn_sched_barrier(0);                                         \
  }

#pragma unroll 1
  for (int t = 0; t < NK; t += 2) {
    TILE8(t, 0)
    TILE8(t + 1, 1)
  }
#undef TILE8
#undef PHASE8
#undef STAGE_A8
#undef STAGE_B8

  if (brow0 < 2048) {
    // ---- fused RoPE epilogue for q/k columns ----
    const bool isq = (brow0 < 1024);
#pragma unroll
    for (int m = 0; m < 8; m++) {
#pragma unroll
      for (int j = 0; j < 4; j++) {
        int p = (j * 16 + fr) >> 1;  // rotation frequency index (wid-independent)
        size_t row0 = (size_t)(arow0 + wm + m * 16 + kq * 4);
        size_t col = (size_t)(brow0 + wn + j * 16 + fr);
#pragma unroll
        for (int r = 0; r < 4; r++) {
          int s_ = (int)((row0 + r) & 2047);
          float2 cs = tab[s_ * 32 + p];
          float v = acc[m][j][r];
          float part = __shfl_xor(v, 1);
          float outv = (fr & 1) ? (part * cs.y + v * cs.x)
                                : (v * cs.x - part * cs.y);
          if (isq) outv *= 0.18033688011112042f;  // 1/8 * log2(e)
          C[(row0 + r) * 3072 + col] = f2bf(outv);
        }
      }
    }
  } else {
#pragma unroll
    for (int m = 0; m < 8; m++) {
#pragma unroll
      for (int j = 0; j < 4; j++) {
        size_t row = (size_t)(arow0 + wm + m * 16 + kq * 4);
        size_t col = (size_t)(brow0 + wn + j * 16 + fr);
#pragma unroll
        for (int r = 0; r < 4; r++)
          C[(row + r) * 3072 + col] = f2bf(acc[m][j][r]);
      }
    }
  }
}

// ===== w_o projection GEMM: 128x64 tiles, counted-vmcnt =====
__global__ __launch_bounds__(256) void gemm_wo(const unsigned short* __restrict__ A,
                                               const unsigned short* __restrict__ B,
                                               float* __restrict__ C, int K) {
  __shared__ unsigned short Ab[2][4096];  // [128][32]
  __shared__ unsigned short Bb[2][2048];  // [64][32]
  const int tid = threadIdx.x;
  const int lane = tid & 63, wid = tid >> 6;
  const int wm = (wid >> 1) * 64, wn = (wid & 1) * 32;
  const int fr = lane & 15, kq = lane >> 4;
  const int arow0 = blockIdx.x * 128;
  const int brow0 = blockIdx.y * 64;

  const int srow = tid >> 2;
  const int schunk = (tid & 3) ^ (srow & 3);
  const unsigned short* aptr = A + (size_t)(arow0 + srow) * K + schunk * 8;
  const unsigned short* bptr = B + (size_t)(brow0 + srow) * K + schunk * 8;

  unsigned int offa[4], offb[2];
#pragma unroll
  for (int i = 0; i < 4; i++)
    offa[i] = (unsigned)((wm + i * 16 + fr) * 64 + ((kq ^ (fr & 3)) * 16));
#pragma unroll
  for (int j = 0; j < 2; j++)
    offb[j] = (unsigned)((wn + j * 16 + fr) * 64 + ((kq ^ (fr & 3)) * 16));

  f32x4 acc[4][2] = {};

#define WSTAGE(BI)                                                 \
  {                                                                \
    gload16(aptr, &Ab[BI][wid * 512]);                             \
    gload16(aptr + (size_t)64 * K, &Ab[BI][2048 + wid * 512]);     \
    gload16(bptr, &Bb[BI][wid * 512]);                             \
    aptr += 32;                                                    \
    bptr += 32;                                                    \
  }

#define WCOMP(BI)                                                                      \
  {                                                                                    \
    bf16x8 af[4], bfr[2];                                                              \
    _Pragma("unroll") for (int i = 0; i < 4; i++) af[i] = lds_read8(Ab[BI], offa[i]);  \
    _Pragma("unroll") for (int j = 0; j < 2; j++) bfr[j] = lds_read8(Bb[BI], offb[j]); \
    _Pragma("unroll") for (int i = 0; i < 4; i++)                                      \
      _Pragma("unroll") for (int j = 0; j < 2; j++)                                    \
        acc[i][j] = __builtin_amdgcn_mfma_f32_16x16x32_bf16(af[i], bfr[j], acc[i][j], 0, 0, 0); \
  }

  const int nk = K >> 5;  // even
  WSTAGE(0);
  for (int ks = 0; ks < nk; ks += 2) {
    asm volatile("s_waitcnt lgkmcnt(0)" ::: "memory");
    __builtin_amdgcn_s_barrier();
    WSTAGE(1);
    asm volatile("s_waitcnt vmcnt(3)" ::: "memory");
    WCOMP(0);
    asm volatile("s_waitcnt lgkmcnt(0)" ::: "memory");
    __builtin_amdgcn_s_barrier();
    if (ks + 2 < nk) {
      WSTAGE(0);
      asm volatile("s_waitcnt vmcnt(3)" ::: "memory");
    } else {
      asm volatile("s_waitcnt vmcnt(0)" ::: "memory");
    }
    WCOMP(1);
  }
#undef WSTAGE
#undef WCOMP

#pragma unroll
  for (int i = 0; i < 4; i++) {
#pragma unroll
    for (int j = 0; j < 2; j++) {
#pragma unroll
      for (int r = 0; r < 4; r++) {
        size_t row = (size_t)(arow0 + wm + i * 16 + kq * 4 + r);
        size_t col = (size_t)(brow0 + wn + j * 16 + fr);
        C[row * 1024 + col] = acc[i][j][r];
      }
    }
  }
}

// ---------- V transpose with pi-permuted s: vt[b][h][d][p] ----------
__global__ __launch_bounds__(256) void vtrans_kernel(const unsigned short* __restrict__ qkv,
                                                     unsigned short* __restrict__ vt) {
  int bid = blockIdx.x;
  int sb = bid & 31;
  int bh = bid >> 5;
  int h = bh & 15, b = bh >> 4;
  __shared__ unsigned short tile[64][72];
  int t = threadIdx.x;
  int sl = t >> 2, c0 = (t & 3) * 16;
  const unsigned short* src = qkv + (size_t)(b * 2048 + sb * 64) * 3072 + 2048 + h * 64;
  *reinterpret_cast<bf16x8*>(&tile[sl][c0]) =
      *reinterpret_cast<const bf16x8*>(&src[(size_t)sl * 3072 + c0]);
  *reinterpret_cast<bf16x8*>(&tile[sl][c0 + 8]) =
      *reinterpret_cast<const bf16x8*>(&src[(size_t)sl * 3072 + c0 + 8]);
  __syncthreads();
  int d = t >> 2, p0 = (t & 3) * 16;
  unsigned short* dst = vt + ((size_t)bh * 64 + d) * 2048 + sb * 64 + p0;
  bf16x8 o0, o1;
#pragma unroll
  for (int i = 0; i < 8; i++) {
    int p = p0 + i;
    int s_in = (p & 32) + ((p >> 2) & 1) * 16 + ((p >> 3) & 3) * 4 + (p & 3);
    o0[i] = (short)tile[s_in][d];
  }
#pragma unroll
  for (int i = 0; i < 8; i++) {
    int p = p0 + 8 + i;
    int s_in = (p & 32) + ((p >> 2) & 1) * 16 + ((p >> 3) & 3) * 4 + (p & 3);
    o1[i] = (short)tile[s_in][d];
  }
  *reinterpret_cast<bf16x8*>(dst) = o0;
  *reinterpret_cast<bf16x8*>(dst + 8) = o1;
}

// ---------- causal flash attention: split-KV, uniform 16/17-step blocks ----------
__global__ __launch_bounds__(256, 4) void attn_kernel(const unsigned short* __restrict__ qkv,
                                                      const unsigned short* __restrict__ vt,
                                                      unsigned short* __restrict__ Y,
                                                      unsigned short* __restrict__ Opart,
                                                      float* __restrict__ Lsum) {
  int bid = blockIdx.x;
  int bh = bid & 31;
  int pair = (bid >> 5) & 15;
  int halfsel = bid >> 9;  // 0 = A, 1 = B
  int h = bh & 15, b = bh >> 4;
  int tid = threadIdx.x, lane = tid & 63, wid = tid >> 6;
  int fr = lane & 15, kq = lane >> 4;

  const size_t mrow0 = (size_t)b * 2048;
  const unsigned short* Kp = qkv + mrow0 * 3072 + 1024 + h * 64;
  const unsigned short* Vp = vt + ((size_t)bh * 64) * 2048;  // [d][p]

  __shared__ unsigned short Klds[2][4096];  // [k:64][d:64], chunk-XOR swizzled
  __shared__ unsigned short Vlds[2][4096];  // [d:64][p:64], chunk-XOR swizzled

  const int srow = tid >> 3;
  const int schunk = (tid & 7) ^ (srow & 7);

  unsigned int offk[8], offv[8];
#pragma unroll
  for (int gg = 0; gg < 4; gg++)
#pragma unroll
    for (int ks = 0; ks < 2; ks++) {
      int R = gg * 16 + fr;
      offk[gg * 2 + ks] = (unsigned)(R * 128 + (((4 * ks + kq) ^ (R & 7)) * 16));
    }
#pragma unroll
  for (int db = 0; db < 4; db++)
#pragma unroll
    for (int hf = 0; hf < 2; hf++) {
      int d = db * 16 + fr;
      offv[db * 2 + hf] = (unsigned)(d * 128 + (((4 * hf + kq) ^ (d & 7)) * 16));
    }

  bf16x8 vones;
#pragma unroll
  for (int i = 0; i < 8; i++) vones[i] = (short)0x3F80;  // bf16 1.0

#define STAGE(BI)                                                     \
  {                                                                   \
    gload16(kstage, &Klds[BI][wid * 512]);                            \
    gload16(kstage + (size_t)32 * 3072, &Klds[BI][2048 + wid * 512]); \
    gload16(vstage, &Vlds[BI][wid * 512]);                            \
    gload16(vstage + 32 * 2048, &Vlds[BI][2048 + wid * 512]);         \
    kstage += (size_t)64 * 3072;                                      \
    vstage += 64;                                                     \
  }

#define TILE_COMPUTE(T, BI)                                                           \
  {                                                                                   \
    const bool masked_ = ((T) == qt_);                                                \
    f32x4 sc[4] = {};                                                                 \
    __builtin_amdgcn_s_setprio(1);                                                    \
    _Pragma("unroll") for (int gg = 0; gg < 4; gg++) {                                \
      _Pragma("unroll") for (int ks = 0; ks < 2; ks++) {                              \
        bf16x8 kf = lds_read8(Klds[BI], offk[gg * 2 + ks]);                           \
        sc[gg] = __builtin_amdgcn_mfma_f32_16x16x32_bf16(kf, qf[ks], sc[gg], 0, 0, 0);\
      }                                                                               \
    }                                                                                 \
    __builtin_amdgcn_s_setprio(0);                                                    \
    float p[16];                                                                      \
    _Pragma("unroll") for (int gg = 0; gg < 4; gg++)                                  \
      _Pragma("unroll") for (int rr = 0; rr < 4; rr++) {                              \
        float v = sc[gg][rr];                                                         \
        if (masked_) {                                                                \
          int k = (T) * 64 + gg * 16 + kq * 4 + rr;                                   \
          if (k > q_lane_) v = -1e30f;                                                \
        }                                                                             \
        p[gg * 4 + rr] = fexp2(v);                                                    \
      }                                                                               \
    u32x4 W0 = {cvtpk_bf16(p[0], p[1]), cvtpk_bf16(p[2], p[3]),                       \
                cvtpk_bf16(p[4], p[5]), cvtpk_bf16(p[6], p[7])};                      \
    u32x4 W1 = {cvtpk_bf16(p[8], p[9]), cvtpk_bf16(p[10], p[11]),                     \
                cvtpk_bf16(p[12], p[13]), cvtpk_bf16(p[14], p[15])};                  \
    bf16x8 pa0 = *reinterpret_cast<bf16x8*>(&W0);                                     \
    bf16x8 pa1 = *reinterpret_cast<bf16x8*>(&W1);                                     \
    __builtin_amdgcn_s_setprio(1);                                                    \
    _Pragma("unroll") for (int db = 0; db < 4; db++) {                                \
      bf16x8 vf0 = lds_read8(Vlds[BI], offv[db * 2]);                                 \
      acc[db] = __builtin_amdgcn_mfma_f32_16x16x32_bf16(vf0, pa0, acc[db], 0, 0, 0);  \
      bf16x8 vf1 = lds_read8(Vlds[BI], offv[db * 2 + 1]);                             \
      acc[db] = __builtin_amdgcn_mfma_f32_16x16x32_bf16(vf1, pa1, acc[db], 0, 0, 0);  \
    }                                                                                 \
    lacc = __builtin_amdgcn_mfma_f32_16x16x32_bf16(vones, pa0, lacc, 0, 0, 0);        \
    lacc = __builtin_amdgcn_mfma_f32_16x16x32_bf16(vones, pa1, lacc, 0, 0, 0);        \
    __builtin_amdgcn_s_setprio(0);                                                    \
  }

  if (halfsel == 0) {
    const int Lt = 31 - pair;
    {
      const int qt_ = Lt;
      const int qbase_ = qt_ * 64 + wid * 16;
      const int q_lane_ = qbase_ + fr;
      const unsigned short* Qp = qkv + (mrow0 + qbase_) * 3072 + h * 64;
      bf16x8 qf[2];
#pragma unroll
      for (int ks = 0; ks < 2; ks++)
        qf[ks] = *reinterpret_cast<const bf16x8*>(&Qp[(size_t)fr * 3072 + ks * 32 + kq * 8]);
      const unsigned short* kstage = Kp + (size_t)srow * 3072 + schunk * 8;
      const unsigned short* vstage = Vp + (size_t)srow * 2048 + schunk * 8;
      f32x4 acc[4] = {};
      f32x4 lacc = {};
      const int nt_ = 16;
      STAGE(0);
      for (int u = 0; u < nt_; u += 2) {
        asm volatile("s_waitcnt lgkmcnt(0)" ::: "memory");
        __builtin_amdgcn_s_barrier();
        if (u + 1 < nt_) {
          STAGE(1);
          asm volatile("s_waitcnt vmcnt(4)" ::: "memory");
        } else {
          asm volatile("s_waitcnt vmcnt(0)" ::: "memory");
        }
        TILE_COMPUTE(u, 0);
        if (u + 1 >= nt_) break;
        asm volatile("s_waitcnt lgkmcnt(0)" ::: "memory");
        __builtin_amdgcn_s_barrier();
        if (u + 2 < nt_) {
          STAGE(0);
          asm volatile("s_waitcnt vmcnt(4)" ::: "memory");
        } else {
          asm volatile("s_waitcnt vmcnt(0)" ::: "memory");
        }
        TILE_COMPUTE(u + 1, 1);
      }
      const int slot = (pair * 2 + 0) * 32 + bh;
      unsigned short* op = Opart + (size_t)slot * 4096;
      int qcol = wid * 16 + fr;
#pragma unroll
      for (int db = 0; db < 4; db++)
#pragma unroll
        for (int rr = 0; rr < 4; rr++) {
          int d = db * 16 + kq * 4 + rr;
          op[d * 64 + qcol] = f2bf(acc[db][rr]);
        }
      if (kq == 0) Lsum[slot * 64 + qcol] = lacc[0];
    }
  } else {
    const int Lt = 31 - pair;
    // phase 1: L tile, KV [16, 32-pair), masked at t = Lt
    {
      const int qt_ = Lt;
      const int qbase_ = qt_ * 64 + wid * 16;
      const int q_lane_ = qbase_ + fr;
      const unsigned short* Qp = qkv + (mrow0 + qbase_) * 3072 + h * 64;
      bf16x8 qf[2];
#pragma unroll
      for (int ks = 0; ks < 2; ks++)
        qf[ks] = *reinterpret_cast<const bf16x8*>(&Qp[(size_t)fr * 3072 + ks * 32 + kq * 8]);
      const unsigned short* kstage = Kp + (size_t)srow * 3072 + schunk * 8 + (size_t)16 * 64 * 3072;
      const unsigned short* vstage = Vp + (size_t)srow * 2048 + schunk * 8 + 16 * 64;
      f32x4 acc[4] = {};
      f32x4 lacc = {};
      const int nt_ = 16 - pair;  // tiles 16 .. 31-pair
      STAGE(0);
      for (int u = 0; u < nt_; u += 2) {
        asm volatile("s_waitcnt lgkmcnt(0)" ::: "memory");
        __builtin_amdgcn_s_barrier();
        if (u + 1 < nt_) {
          STAGE(1);
          asm volatile("s_waitcnt vmcnt(4)" ::: "memory");
        } else {
          asm volatile("s_waitcnt vmcnt(0)" ::: "memory");
        }
        TILE_COMPUTE(16 + u, 0);
        if (u + 1 >= nt_) break;
        asm volatile("s_waitcnt lgkmcnt(0)" ::: "memory");
        __builtin_amdgcn_s_barrier();
        if (u + 2 < nt_) {
          STAGE(0);
          asm volatile("s_waitcnt vmcnt(4)" ::: "memory");
        } else {
          asm volatile("s_waitcnt vmcnt(0)" ::: "memory");
        }
        TILE_COMPUTE(16 + u + 1, 1);
      }
      const int slot = (pair * 2 + 1) * 32 + bh;
      unsigned short* op = Opart + (size_t)slot * 4096;
      int qcol = wid * 16 + fr;
#pragma unroll
      for (int db = 0; db < 4; db++)
#pragma unroll
        for (int rr = 0; rr < 4; rr++) {
          int d = db * 16 + kq * 4 + rr;
          op[d * 64 + qcol] = f2bf(acc[db][rr]);
        }
      if (kq == 0) Lsum[slot * 64 + qcol] = lacc[0];
    }
    // inter-phase: all waves' LDS reads done before phase-2 STAGE overwrites
    asm volatile("s_waitcnt lgkmcnt(0) vmcnt(0)" ::: "memory");
    __builtin_amdgcn_s_barrier();
    // phase 2: S tile = pair, KV [0, pair+1), masked at t = pair; direct write
    {
      const int qt_ = pair;
      const int qbase_ = qt_ * 64 + wid * 16;
      const int q_lane_ = qbase_ + fr;
      const unsigned short* Qp = qkv + (mrow0 + qbase_) * 3072 + h * 64;
      bf16x8 qf[2];
#pragma unroll
      for (int ks = 0; ks < 2; ks++)
        qf[ks] = *reinterpret_cast<const bf16x8*>(&Qp[(size_t)fr * 3072 + ks * 32 + kq * 8]);
      const unsigned short* kstage = Kp + (size_t)srow * 3072 + schunk * 8;
      const unsigned short* vstage = Vp + (size_t)srow * 2048 + schunk * 8;
      f32x4 acc[4] = {};
      f32x4 lacc = {};
      const int nt_ = pair + 1;
      STAGE(0);
      for (int u = 0; u < nt_; u += 2) {
        asm volatile("s_waitcnt lgkmcnt(0)" ::: "memory");
        __builtin_amdgcn_s_barrier();
        if (u + 1 < nt_) {
          STAGE(1);
          asm volatile("s_waitcnt vmcnt(4)" ::: "memory");
        } else {
          asm volatile("s_waitcnt vmcnt(0)" ::: "memory");
        }
        TILE_COMPUTE(u, 0);
        if (u + 1 >= nt_) break;
        asm volatile("s_waitcnt lgkmcnt(0)" ::: "memory");
        __builtin_amdgcn_s_barrier();
        if (u + 2 < nt_) {
          STAGE(0);
          asm volatile("s_waitcnt vmcnt(4)" ::: "memory");
        } else {
          asm volatile("s_waitcnt vmcnt(0)" ::: "memory");
        }
        TILE_COMPUTE(u + 1, 1);
      }
      float inv = 1.0f / lacc[0];
      unsigned short* yp = Y + (mrow0 + qbase_ + fr) * 1024 + h * 64 + kq * 4;
#pragma unroll
      for (int db = 0; db < 4; db++) {
        ushort4 o;
        o.x = f2bf(acc[db][0] * inv);
        o.y = f2bf(acc[db][1] * inv);
        o.z = f2bf(acc[db][2] * inv);
        o.w = f2bf(acc[db][3] * inv);
        *reinterpret_cast<ushort4*>(yp + db * 16) = o;
      }
    }
  }
#undef TILE_COMPUTE
#undef STAGE
}

// ---------- combine partials for L tiles (q-tiles 16..31) ----------
__global__ __launch_bounds__(256) void attn_combine(const unsigned short* __restrict__ Opart,
                                                    const float* __restrict__ Lsum,
                                                    unsigned short* __restrict__ Y) {
  int bid = blockIdx.x;     // 512 = 16 pairs x 32 bh
  int pair = bid >> 5;
  int bh = bid & 31;
  int Lt = 31 - pair;
  int h = bh & 15, b = bh >> 4;
  int t = threadIdx.x;
  int q = t >> 2, d0 = (t & 3) * 16;
  size_t s0 = (size_t)((pair * 2 + 0) * 32 + bh);
  size_t s1 = (size_t)((pair * 2 + 1) * 32 + bh);
  float inv = 1.0f / (Lsum[s0 * 64 + q] + Lsum[s1 * 64 + q]);
  const unsigned short* p0 = Opart + s0 * 4096;
  const unsigned short* p1 = Opart + s1 * 4096;
  bf16x8 o0, o1;
#pragma unroll
  for (int i = 0; i < 8; i++) {
    int d = d0 + i;
    o0[i] = (short)f2bf((bf2f(p0[d * 64 + q]) + bf2f(p1[d * 64 + q])) * inv);
  }
#pragma unroll
  for (int i = 0; i < 8; i++) {
    int d = d0 + 8 + i;
    o1[i] = (short)f2bf((bf2f(p0[d * 64 + q]) + bf2f(p1[d * 64 + q])) * inv);
  }
  unsigned short* yp = Y + ((size_t)(b * 2048 + Lt * 64 + q)) * 1024 + h * 64 + d0;
  *reinterpret_cast<bf16x8*>(yp) = o0;
  *reinterpret_cast<bf16x8*>(yp + 8) = o1;
}

// ---------- launch ----------
extern "C" void kernel_launch(void* const* d_in, const int* in_sizes, int n_in,
                              void* d_out, int out_size, void* d_ws, size_t ws_size,
                              hipStream_t stream) {
  const float* x     = (const float*)d_in[0];   // [2,2048,1024]
  const float* w_qkv = (const float*)d_in[1];   // [3072,1024]
  const float* w_o   = (const float*)d_in[2];   // [1024,1024]
  const int*   pos   = (const int*)d_in[3];     // [2048]
  float* out = (float*)d_out;                   // [2,2048,1024] f32

  unsigned char* ws = (unsigned char*)d_ws;
  unsigned short* x_bf    = (unsigned short*)(ws);               //  8,388,608 B
  unsigned short* wqkv_bf = (unsigned short*)(ws + 8388608);     //  6,291,456 B
  unsigned short* wo_bf   = (unsigned short*)(ws + 14680064);    //  2,097,152 B
  unsigned short* qkv     = (unsigned short*)(ws + 16777216);    // 25,165,824 B
  unsigned short* vt      = (unsigned short*)(ws + 41943040);    //  8,388,608 B
  unsigned short* y       = (unsigned short*)(ws + 50331648);    //  8,388,608 B
  // attn scratch reuses regions dead after gemm8:
  unsigned short* Opart = x_bf;                  // 8,388,608 B
  float* Lsum = (float*)wqkv_bf;                 //   262,144 B
  // RoPE cos/sin table lives in vt region (dead until vtrans runs after gemm8)
  float2* tab = (float2*)vt;                     //   524,288 B

  cvt3_f32_bf16<<<1536, 256, 0, stream>>>(x, x_bf, 4096 * 1024 / 4,
                                          w_qkv, wqkv_bf, 3072 * 1024 / 4,
                                          w_o, wo_bf, 1024 * 1024 / 4,
                                          pos, tab);

  gemm8_qkv<<<192, 512, 0, stream>>>(x_bf, wqkv_bf, qkv, tab);

  vtrans_kernel<<<1024, 256, 0, stream>>>(qkv, vt);

  attn_kernel<<<1024, 256, 0, stream>>>(qkv, vt, y, Opart, Lsum);
  attn_combine<<<512, 256, 0, stream>>>(Opart, Lsum, y);

  gemm_wo<<<dim3(32, 16), 256, 0, stream>>>(y, wo_bf, out, 1024);
}

// Round 22
// 101.679 us; speedup vs baseline: 1.0392x; 1.0392x over previous
//
#include <hip/hip_runtime.h>
#include <math.h>

#define DEV __device__ __forceinline__

typedef __attribute__((ext_vector_type(8))) short bf16x8;
typedef __attribute__((ext_vector_type(4))) float f32x4;
typedef __attribute__((ext_vector_type(4))) unsigned int u32x4;

typedef __attribute__((address_space(3))) unsigned int lds_u32;
typedef const __attribute__((address_space(1))) unsigned int glb_u32;

// async global->LDS, 16B per lane; lds dest = wave-uniform base + lane*16
DEV void gload16(const unsigned short* g, unsigned short* l) {
  __builtin_amdgcn_global_load_lds((glb_u32*)g, (lds_u32*)l, 16, 0, 0);
}

// LDS vector read at precomputed byte offset
DEV bf16x8 lds_read8(const unsigned short* base, unsigned int byteoff) {
  return *reinterpret_cast<const bf16x8*>(
      reinterpret_cast<const char*>(base) + byteoff);
}

// native v_exp_f32 (2^x), 1 instruction
DEV float fexp2(float x) { return __builtin_amdgcn_exp2f(x); }

// ---------- bf16 helpers ----------
DEV unsigned short f2bf(float f) {
  union { float f; unsigned int u; } v; v.f = f;
  unsigned int u = v.u;
  unsigned int r = (u + 0x7fffu + ((u >> 16) & 1u)) >> 16;
  return (unsigned short)r;
}
DEV float bf2f(unsigned short h) {
  union { unsigned int u; float f; } v; v.u = ((unsigned int)h) << 16;
  return v.f;
}
DEV unsigned int cvtpk_bf16(float lo, float hi) {
  unsigned int r;
  asm("v_cvt_pk_bf16_f32 %0, %1, %2" : "=v"(r) : "v"(lo), "v"(hi));
  return r;
}

// ---------- fp32 -> bf16 convert, three buffers in one launch ----------
__global__ void cvt3_f32_bf16(const float* __restrict__ ina,
                              unsigned short* __restrict__ outa, int n4a,
                              const float* __restrict__ inb,
                              unsigned short* __restrict__ outb, int n4b,
                              const float* __restrict__ inc,
                              unsigned short* __restrict__ outc, int n4c) {
  int stride = gridDim.x * blockDim.x;
  int total = n4a + n4b + n4c;
  for (int i = blockIdx.x * blockDim.x + threadIdx.x; i < total; i += stride) {
    const float* src;
    unsigned short* dst;
    int j = i;
    if (j < n4a) {
      src = ina; dst = outa;
    } else if ((j -= n4a) < n4b) {
      src = inb; dst = outb;
    } else {
      j -= n4b; src = inc; dst = outc;
    }
    float4 f = reinterpret_cast<const float4*>(src)[j];
    ushort4 o;
    o.x = f2bf(f.x); o.y = f2bf(f.y); o.z = f2bf(f.z); o.w = f2bf(f.w);
    reinterpret_cast<ushort4*>(dst)[j] = o;
  }
}

// ================= 256x192 8-phase GEMM for QKV =================
// C[4096,3072] = A[4096,1024]*B[3072,1024]^T bf16. Grid 256 = 16x16 tiles:
// exactly 1 block per CU, zero idle CUs (256x256 gave 192 blocks / 64 idle CUs).
// 512 thr / 8 waves (2M x 4N); per-wave 128x48 (acc[8][3]). BK=64; LDS 112KB
// (A 32KB + B 24KB, double-buffered). Counted vmcnt(3): per tile 4 A-loads +
// 3 B-loads; P0 issues A(t+1), P1 2xB(t+2), P2 1xB(t+2).
__global__ __launch_bounds__(512, 2) void gemm8_qkv(const unsigned short* __restrict__ A,
                                                    const unsigned short* __restrict__ B,
                                                    unsigned short* __restrict__ C) {
  constexpr int K = 1024;
  constexpr int NK = 16;  // K / 64
  __shared__ unsigned short Ls[2][28672];  // A shorts [0,16384), B [16384,28672)

  const int tid = threadIdx.x;
  const int lane = tid & 63, wid = tid >> 6;
  const int wm = (wid >> 2) * 128;  // 0 / 128
  const int wn = (wid & 3) * 48;    // 0,48,96,144
  const int fr = lane & 15, kq = lane >> 4;

  int bid = blockIdx.x;
  int swz = (bid & 7) * 32 + (bid >> 3);  // bijective, XCD gets 2 B-panels
  int tm = swz & 15, tn = swz >> 4;       // 16 x 16
  const int arow0 = tm * 256, brow0 = tn * 192;

  const int subrow = lane >> 3;
  const int scol = ((lane & 7) ^ subrow) * 8;
  const unsigned short* aSrc = A + (size_t)(arow0 + wid * 8 + subrow) * K + scol;
  const unsigned short* bSrc = B + (size_t)(brow0 + wid * 8 + subrow) * K + scol;

  unsigned aoff[2], boff[2];
#pragma unroll
  for (int ks = 0; ks < 2; ks++) {
    unsigned x = ((unsigned)((ks * 4 + kq) ^ (fr & 7))) * 16;
    aoff[ks] = (unsigned)((wm + fr) * 128) + x;
    boff[ks] = 32768u + (unsigned)((wn + fr) * 128) + x;
  }

  f32x4 acc[8][3] = {};

#define STAGE_A8(BUF, T)                                                     \
  {                                                                          \
    _Pragma("unroll") for (int H = 0; H < 4; H++)                            \
      gload16(aSrc + (size_t)(H * 64) * K + (T) * 64,                        \
              &Ls[BUF][(H * 64 + wid * 8) * 64]);                            \
  }
#define STAGE_B2(BUF, T)                                                     \
  {                                                                          \
    _Pragma("unroll") for (int H = 0; H < 2; H++)                            \
      gload16(bSrc + (size_t)(H * 64) * K + (T) * 64,                        \
              &Ls[BUF][16384 + (H * 64 + wid * 8) * 64]);                    \
  }
#define STAGE_B1(BUF, T)                                                     \
  {                                                                          \
    gload16(bSrc + (size_t)(2 * 64) * K + (T) * 64,                          \
            &Ls[BUF][16384 + (2 * 64 + wid * 8) * 64]);                      \
  }

  // prologue: tile0 (A+B) + tile1 (B only); wait tile0 resident, B(1) in flight
  STAGE_A8(0, 0)
  STAGE_B2(0, 0) STAGE_B1(0, 0)
  STAGE_B2(1, 1) STAGE_B1(1, 1)
  asm volatile("s_waitcnt vmcnt(3)" ::: "memory");
  __builtin_amdgcn_s_barrier();

#define PHASE8(BUF, P, DO_STAGE)                                              \
  {                                                                           \
    bf16x8 af[2][2];                                                          \
    _Pragma("unroll") for (int mm = 0; mm < 2; mm++)                          \
      _Pragma("unroll") for (int ks = 0; ks < 2; ks++)                        \
        af[mm][ks] = lds_read8(Ls[BUF], aoff[ks] + ((P) * 2 + mm) * 2048);    \
    DO_STAGE                                                                  \
    __builtin_amdgcn_s_setprio(1);                                            \
    _Pragma("unroll") for (int mm = 0; mm < 2; mm++)                          \
      _Pragma("unroll") for (int j = 0; j < 3; j++)                           \
        _Pragma("unroll") for (int ks = 0; ks < 2; ks++)                      \
          acc[(P) * 2 + mm][j] = __builtin_amdgcn_mfma_f32_16x16x32_bf16(     \
              af[mm][ks], bq[j][ks], acc[(P) * 2 + mm][j], 0, 0, 0);          \
    __builtin_amdgcn_s_setprio(0);                                            \
  }

#define TILE8(T, BUF)                                                          \
  {                                                                            \
    bf16x8 bq[3][2];                                                           \
    _Pragma("unroll") for (int j = 0; j < 3; j++)                              \
      _Pragma("unroll") for (int ks = 0; ks < 2; ks++)                         \
        bq[j][ks] = lds_read8(Ls[BUF], boff[ks] + j * 2048);                   \
    PHASE8(BUF, 0, { if ((T) + 1 < NK) STAGE_A8(BUF ^ 1, (T) + 1) })           \
    __builtin_amdgcn_s_barrier();                                              \
    PHASE8(BUF, 1, { if ((T) + 2 < NK) STAGE_B2(BUF, (T) + 2) })               \
    __builtin_amdgcn_s_barrier();                                              \
    PHASE8(BUF, 2, { if ((T) + 2 < NK) STAGE_B1(BUF, (T) + 2) })               \
    __builtin_amdgcn_s_barrier();                                              \
    PHASE8(BUF, 3, {})                                                         \
    if ((T) + 2 < NK) {                                                        \
      asm volatile("s_waitcnt vmcnt(3)" ::: "memory");                         \
    } else {                                                                   \
      asm volatile("s_waitcnt vmcnt(0)" ::: "memory");                         \
    }                                                                          \
    __builtin_amdgcn_s_barrier();                                              \
    __builtin_amdgcn_sched_barrier(0);                                         \
  }

#pragma unroll 1
  for (int t = 0; t < NK; t += 2) {
    TILE8(t, 0)
    TILE8(t + 1, 1)
  }
#undef TILE8
#undef PHASE8
#undef STAGE_A8
#undef STAGE_B2
#undef STAGE_B1

#pragma unroll
  for (int m = 0; m < 8; m++) {
#pragma unroll
    for (int j = 0; j < 3; j++) {
      size_t row = (size_t)(arow0 + wm + m * 16 + kq * 4);
      size_t col = (size_t)(brow0 + wn + j * 16 + fr);
#pragma unroll
      for (int r = 0; r < 4; r++)
        C[(row + r) * 3072 + col] = f2bf(acc[m][j][r]);
    }
  }
}

// ===== w_o projection GEMM: 128x64 tiles, counted-vmcnt =====
__global__ __launch_bounds__(256) void gemm_wo(const unsigned short* __restrict__ A,
                                               const unsigned short* __restrict__ B,
                                               float* __restrict__ C, int K) {
  __shared__ unsigned short Ab[2][4096];  // [128][32]
  __shared__ unsigned short Bb[2][2048];  // [64][32]
  const int tid = threadIdx.x;
  const int lane = tid & 63, wid = tid >> 6;
  const int wm = (wid >> 1) * 64, wn = (wid & 1) * 32;
  const int fr = lane & 15, kq = lane >> 4;
  const int arow0 = blockIdx.x * 128;
  const int brow0 = blockIdx.y * 64;

  const int srow = tid >> 2;
  const int schunk = (tid & 3) ^ (srow & 3);
  const unsigned short* aptr = A + (size_t)(arow0 + srow) * K + schunk * 8;
  const unsigned short* bptr = B + (size_t)(brow0 + srow) * K + schunk * 8;

  unsigned int offa[4], offb[2];
#pragma unroll
  for (int i = 0; i < 4; i++)
    offa[i] = (unsigned)((wm + i * 16 + fr) * 64 + ((kq ^ (fr & 3)) * 16));
#pragma unroll
  for (int j = 0; j < 2; j++)
    offb[j] = (unsigned)((wn + j * 16 + fr) * 64 + ((kq ^ (fr & 3)) * 16));

  f32x4 acc[4][2] = {};

#define WSTAGE(BI)                                                 \
  {                                                                \
    gload16(aptr, &Ab[BI][wid * 512]);                             \
    gload16(aptr + (size_t)64 * K, &Ab[BI][2048 + wid * 512]);     \
    gload16(bptr, &Bb[BI][wid * 512]);                             \
    aptr += 32;                                                    \
    bptr += 32;                                                    \
  }

#define WCOMP(BI)                                                                      \
  {                                                                                    \
    bf16x8 af[4], bfr[2];                                                              \
    _Pragma("unroll") for (int i = 0; i < 4; i++) af[i] = lds_read8(Ab[BI], offa[i]);  \
    _Pragma("unroll") for (int j = 0; j < 2; j++) bfr[j] = lds_read8(Bb[BI], offb[j]); \
    _Pragma("unroll") for (int i = 0; i < 4; i++)                                      \
      _Pragma("unroll") for (int j = 0; j < 2; j++)                                    \
        acc[i][j] = __builtin_amdgcn_mfma_f32_16x16x32_bf16(af[i], bfr[j], acc[i][j], 0, 0, 0); \
  }

  const int nk = K >> 5;  // even
  WSTAGE(0);
  for (int ks = 0; ks < nk; ks += 2) {
    asm volatile("s_waitcnt lgkmcnt(0)" ::: "memory");
    __builtin_amdgcn_s_barrier();
    WSTAGE(1);
    asm volatile("s_waitcnt vmcnt(3)" ::: "memory");
    WCOMP(0);
    asm volatile("s_waitcnt lgkmcnt(0)" ::: "memory");
    __builtin_amdgcn_s_barrier();
    if (ks + 2 < nk) {
      WSTAGE(0);
      asm volatile("s_waitcnt vmcnt(3)" ::: "memory");
    } else {
      asm volatile("s_waitcnt vmcnt(0)" ::: "memory");
    }
    WCOMP(1);
  }
#undef WSTAGE
#undef WCOMP

#pragma unroll
  for (int i = 0; i < 4; i++) {
#pragma unroll
    for (int j = 0; j < 2; j++) {
#pragma unroll
      for (int r = 0; r < 4; r++) {
        size_t row = (size_t)(arow0 + wm + i * 16 + kq * 4 + r);
        size_t col = (size_t)(brow0 + wn + j * 16 + fr);
        C[row * 1024 + col] = acc[i][j][r];
      }
    }
  }
}

// ---------- fused RoPE (blocks 0..4095) + V-transpose (blocks 4096..5119) ----------
__global__ __launch_bounds__(256) void rope_vtrans_kernel(unsigned short* __restrict__ qkv,
                                                          const int* __restrict__ pos,
                                                          unsigned short* __restrict__ vt) {
  int bid0 = blockIdx.x;
  int t = threadIdx.x;
  if (bid0 < 4096) {
    int m = bid0;
    int s = m & 2047;
    __shared__ float Cl[32], Sl[32];
    if (t < 32) {
      float position = (float)pos[s];
      float inv = __expf(-(float)t * (9.210340371976184f / 32.0f));
      float ang = position * inv;
      Cl[t] = cosf(ang);
      Sl[t] = sinf(ang);
    }
    __syncthreads();
    const float QS = 0.18033688011112042f;  // 1/8 * log2(e)
    int h = t >> 4, g = t & 15;
    float c0 = Cl[2 * g], s0 = Sl[2 * g], c1 = Cl[2 * g + 1], s1 = Sl[2 * g + 1];
    size_t base = (size_t)m * 3072 + h * 64 + 4 * g;
    ushort4 qv = *reinterpret_cast<ushort4*>(&qkv[base]);
    float qe0 = bf2f(qv.x), qo0 = bf2f(qv.y), qe1 = bf2f(qv.z), qo1 = bf2f(qv.w);
    qv.x = f2bf((qe0 * c0 - qo0 * s0) * QS);
    qv.y = f2bf((qe0 * s0 + qo0 * c0) * QS);
    qv.z = f2bf((qe1 * c1 - qo1 * s1) * QS);
    qv.w = f2bf((qe1 * s1 + qo1 * c1) * QS);
    *reinterpret_cast<ushort4*>(&qkv[base]) = qv;
    size_t kb = base + 1024;
    ushort4 kv = *reinterpret_cast<ushort4*>(&qkv[kb]);
    float ke0 = bf2f(kv.x), ko0 = bf2f(kv.y), ke1 = bf2f(kv.z), ko1 = bf2f(kv.w);
    kv.x = f2bf(ke0 * c0 - ko0 * s0);
    kv.y = f2bf(ke0 * s0 + ko0 * c0);
    kv.z = f2bf(ke1 * c1 - ko1 * s1);
    kv.w = f2bf(ke1 * s1 + ko1 * c1);
    *reinterpret_cast<ushort4*>(&qkv[kb]) = kv;
  } else {
    int bid = bid0 - 4096;
    int sb = bid & 31;
    int bh = bid >> 5;
    int h = bh & 15, b = bh >> 4;
    __shared__ unsigned short tile[64][72];
    int sl = t >> 2, c0 = (t & 3) * 16;
    const unsigned short* src = qkv + (size_t)(b * 2048 + sb * 64) * 3072 + 2048 + h * 64;
    *reinterpret_cast<bf16x8*>(&tile[sl][c0]) =
        *reinterpret_cast<const bf16x8*>(&src[(size_t)sl * 3072 + c0]);
    *reinterpret_cast<bf16x8*>(&tile[sl][c0 + 8]) =
        *reinterpret_cast<const bf16x8*>(&src[(size_t)sl * 3072 + c0 + 8]);
    __syncthreads();
    int d = t >> 2, p0 = (t & 3) * 16;
    unsigned short* dst = vt + ((size_t)bh * 64 + d) * 2048 + sb * 64 + p0;
    bf16x8 o0, o1;
#pragma unroll
    for (int i = 0; i < 8; i++) {
      int p = p0 + i;
      int s_in = (p & 32) + ((p >> 2) & 1) * 16 + ((p >> 3) & 3) * 4 + (p & 3);
      o0[i] = (short)tile[s_in][d];
    }
#pragma unroll
    for (int i = 0; i < 8; i++) {
      int p = p0 + 8 + i;
      int s_in = (p & 32) + ((p >> 2) & 1) * 16 + ((p >> 3) & 3) * 4 + (p & 3);
      o1[i] = (short)tile[s_in][d];
    }
    *reinterpret_cast<bf16x8*>(dst) = o0;
    *reinterpret_cast<bf16x8*>(dst + 8) = o1;
  }
}

// ---------- causal flash attention: split-KV, uniform 16/17-step blocks ----------
__global__ __launch_bounds__(256, 4) void attn_kernel(const unsigned short* __restrict__ qkv,
                                                      const unsigned short* __restrict__ vt,
                                                      unsigned short* __restrict__ Y,
                                                      unsigned short* __restrict__ Opart,
                                                      float* __restrict__ Lsum) {
  int bid = blockIdx.x;
  int bh = bid & 31;
  int pair = (bid >> 5) & 15;
  int halfsel = bid >> 9;  // 0 = A, 1 = B
  int h = bh & 15, b = bh >> 4;
  int tid = threadIdx.x, lane = tid & 63, wid = tid >> 6;
  int fr = lane & 15, kq = lane >> 4;

  const size_t mrow0 = (size_t)b * 2048;
  const unsigned short* Kp = qkv + mrow0 * 3072 + 1024 + h * 64;
  const unsigned short* Vp = vt + ((size_t)bh * 64) * 2048;  // [d][p]

  __shared__ unsigned short Klds[2][4096];  // [k:64][d:64], chunk-XOR swizzled
  __shared__ unsigned short Vlds[2][4096];  // [d:64][p:64], chunk-XOR swizzled

  const int srow = tid >> 3;
  const int schunk = (tid & 7) ^ (srow & 7);

  unsigned int offk[8], offv[8];
#pragma unroll
  for (int gg = 0; gg < 4; gg++)
#pragma unroll
    for (int ks = 0; ks < 2; ks++) {
      int R = gg * 16 + fr;
      offk[gg * 2 + ks] = (unsigned)(R * 128 + (((4 * ks + kq) ^ (R & 7)) * 16));
    }
#pragma unroll
  for (int db = 0; db < 4; db++)
#pragma unroll
    for (int hf = 0; hf < 2; hf++) {
      int d = db * 16 + fr;
      offv[db * 2 + hf] = (unsigned)(d * 128 + (((4 * hf + kq) ^ (d & 7)) * 16));
    }

  bf16x8 vones;
#pragma unroll
  for (int i = 0; i < 8; i++) vones[i] = (short)0x3F80;  // bf16 1.0

#define STAGE(BI)                                                     \
  {                                                                   \
    gload16(kstage, &Klds[BI][wid * 512]);                            \
    gload16(kstage + (size_t)32 * 3072, &Klds[BI][2048 + wid * 512]); \
    gload16(vstage, &Vlds[BI][wid * 512]);                            \
    gload16(vstage + 32 * 2048, &Vlds[BI][2048 + wid * 512]);         \
    kstage += (size_t)64 * 3072;                                      \
    vstage += 64;                                                     \
  }

#define TILE_COMPUTE(T, BI)                                                           \
  {                                                                                   \
    const bool masked_ = ((T) == qt_);                                                \
    f32x4 sc[4] = {};                                                                 \
    __builtin_amdgcn_s_setprio(1);                                                    \
    _Pragma("unroll") for (int gg = 0; gg < 4; gg++) {                                \
      _Pragma("unroll") for (int ks = 0; ks < 2; ks++) {                              \
        bf16x8 kf = lds_read8(Klds[BI], offk[gg * 2 + ks]);                           \
        sc[gg] = __builtin_amdgcn_mfma_f32_16x16x32_bf16(kf, qf[ks], sc[gg], 0, 0, 0);\
      }                                                                               \
    }                                                                                 \
    __builtin_amdgcn_s_setprio(0);                                                    \
    float p[16];                                                                      \
    _Pragma("unroll") for (int gg = 0; gg < 4; gg++)                                  \
      _Pragma("unroll") for (int rr = 0; rr < 4; rr++) {                              \
        float v = sc[gg][rr];                                                         \
        if (masked_) {                                                                \
          int k = (T) * 64 + gg * 16 + kq * 4 + rr;                                   \
          if (k > q_lane_) v = -1e30f;                                                \
        }                                                                             \
        p[gg * 4 + rr] = fexp2(v);                                                    \
      }                                                                               \
    u32x4 W0 = {cvtpk_bf16(p[0], p[1]), cvtpk_bf16(p[2], p[3]),                       \
                cvtpk_bf16(p[4], p[5]), cvtpk_bf16(p[6], p[7])};                      \
    u32x4 W1 = {cvtpk_bf16(p[8], p[9]), cvtpk_bf16(p[10], p[11]),                     \
                cvtpk_bf16(p[12], p[13]), cvtpk_bf16(p[14], p[15])};                  \
    bf16x8 pa0 = *reinterpret_cast<bf16x8*>(&W0);                                     \
    bf16x8 pa1 = *reinterpret_cast<bf16x8*>(&W1);                                     \
    __builtin_amdgcn_s_setprio(1);                                                    \
    _Pragma("unroll") for (int db = 0; db < 4; db++) {                                \
      bf16x8 vf0 = lds_read8(Vlds[BI], offv[db * 2]);                                 \
      acc[db] = __builtin_amdgcn_mfma_f32_16x16x32_bf16(vf0, pa0, acc[db], 0, 0, 0);  \
      bf16x8 vf1 = lds_read8(Vlds[BI], offv[db * 2 + 1]);                             \
      acc[db] = __builtin_amdgcn_mfma_f32_16x16x32_bf16(vf1, pa1, acc[db], 0, 0, 0);  \
    }                                                                                 \
    lacc = __builtin_amdgcn_mfma_f32_16x16x32_bf16(vones, pa0, lacc, 0, 0, 0);        \
    lacc = __builtin_amdgcn_mfma_f32_16x16x32_bf16(vones, pa1, lacc, 0, 0, 0);        \
    __builtin_amdgcn_s_setprio(0);                                                    \
  }

  if (halfsel == 0) {
    const int Lt = 31 - pair;
    {
      const int qt_ = Lt;
      const int qbase_ = qt_ * 64 + wid * 16;
      const int q_lane_ = qbase_ + fr;
      const unsigned short* Qp = qkv + (mrow0 + qbase_) * 3072 + h * 64;
      bf16x8 qf[2];
#pragma unroll
      for (int ks = 0; ks < 2; ks++)
        qf[ks] = *reinterpret_cast<const bf16x8*>(&Qp[(size_t)fr * 3072 + ks * 32 + kq * 8]);
      const unsigned short* kstage = Kp + (size_t)srow * 3072 + schunk * 8;
      const unsigned short* vstage = Vp + (size_t)srow * 2048 + schunk * 8;
      f32x4 acc[4] = {};
      f32x4 lacc = {};
      const int nt_ = 16;
      STAGE(0);
      for (int u = 0; u < nt_; u += 2) {
        asm volatile("s_waitcnt lgkmcnt(0)" ::: "memory");
        __builtin_amdgcn_s_barrier();
        if (u + 1 < nt_) {
          STAGE(1);
          asm volatile("s_waitcnt vmcnt(4)" ::: "memory");
        } else {
          asm volatile("s_waitcnt vmcnt(0)" ::: "memory");
        }
        TILE_COMPUTE(u, 0);
        if (u + 1 >= nt_) break;
        asm volatile("s_waitcnt lgkmcnt(0)" ::: "memory");
        __builtin_amdgcn_s_barrier();
        if (u + 2 < nt_) {
          STAGE(0);
          asm volatile("s_waitcnt vmcnt(4)" ::: "memory");
        } else {
          asm volatile("s_waitcnt vmcnt(0)" ::: "memory");
        }
        TILE_COMPUTE(u + 1, 1);
      }
      const int slot = (pair * 2 + 0) * 32 + bh;
      unsigned short* op = Opart + (size_t)slot * 4096;
      int qcol = wid * 16 + fr;
#pragma unroll
      for (int db = 0; db < 4; db++)
#pragma unroll
        for (int rr = 0; rr < 4; rr++) {
          int d = db * 16 + kq * 4 + rr;
          op[d * 64 + qcol] = f2bf(acc[db][rr]);
        }
      if (kq == 0) Lsum[slot * 64 + qcol] = lacc[0];
    }
  } else {
    const int Lt = 31 - pair;
    // phase 1: L tile, KV [16, 32-pair), masked at t = Lt
    {
      const int qt_ = Lt;
      const int qbase_ = qt_ * 64 + wid * 16;
      const int q_lane_ = qbase_ + fr;
      const unsigned short* Qp = qkv + (mrow0 + qbase_) * 3072 + h * 64;
      bf16x8 qf[2];
#pragma unroll
      for (int ks = 0; ks < 2; ks++)
        qf[ks] = *reinterpret_cast<const bf16x8*>(&Qp[(size_t)fr * 3072 + ks * 32 + kq * 8]);
      const unsigned short* kstage = Kp + (size_t)srow * 3072 + schunk * 8 + (size_t)16 * 64 * 3072;
      const unsigned short* vstage = Vp + (size_t)srow * 2048 + schunk * 8 + 16 * 64;
      f32x4 acc[4] = {};
      f32x4 lacc = {};
      const int nt_ = 16 - pair;  // tiles 16 .. 31-pair
      STAGE(0);
      for (int u = 0; u < nt_; u += 2) {
        asm volatile("s_waitcnt lgkmcnt(0)" ::: "memory");
        __builtin_amdgcn_s_barrier();
        if (u + 1 < nt_) {
          STAGE(1);
          asm volatile("s_waitcnt vmcnt(4)" ::: "memory");
        } else {
          asm volatile("s_waitcnt vmcnt(0)" ::: "memory");
        }
        TILE_COMPUTE(16 + u, 0);
        if (u + 1 >= nt_) break;
        asm volatile("s_waitcnt lgkmcnt(0)" ::: "memory");
        __builtin_amdgcn_s_barrier();
        if (u + 2 < nt_) {
          STAGE(0);
          asm volatile("s_waitcnt vmcnt(4)" ::: "memory");
        } else {
          asm volatile("s_waitcnt vmcnt(0)" ::: "memory");
        }
        TILE_COMPUTE(16 + u + 1, 1);
      }
      const int slot = (pair * 2 + 1) * 32 + bh;
      unsigned short* op = Opart + (size_t)slot * 4096;
      int qcol = wid * 16 + fr;
#pragma unroll
      for (int db = 0; db < 4; db++)
#pragma unroll
        for (int rr = 0; rr < 4; rr++) {
          int d = db * 16 + kq * 4 + rr;
          op[d * 64 + qcol] = f2bf(acc[db][rr]);
        }
      if (kq == 0) Lsum[slot * 64 + qcol] = lacc[0];
    }
    // inter-phase: all waves' LDS reads done before phase-2 STAGE overwrites
    asm volatile("s_waitcnt lgkmcnt(0) vmcnt(0)" ::: "memory");
    __builtin_amdgcn_s_barrier();
    // phase 2: S tile = pair, KV [0, pair+1), masked at t = pair; direct write
    {
      const int qt_ = pair;
      const int qbase_ = qt_ * 64 + wid * 16;
      const int q_lane_ = qbase_ + fr;
      const unsigned short* Qp = qkv + (mrow0 + qbase_) * 3072 + h * 64;
      bf16x8 qf[2];
#pragma unroll
      for (int ks = 0; ks < 2; ks++)
        qf[ks] = *reinterpret_cast<const bf16x8*>(&Qp[(size_t)fr * 3072 + ks * 32 + kq * 8]);
      const unsigned short* kstage = Kp + (size_t)srow * 3072 + schunk * 8;
      const unsigned short* vstage = Vp + (size_t)srow * 2048 + schunk * 8;
      f32x4 acc[4] = {};
      f32x4 lacc = {};
      const int nt_ = pair + 1;
      STAGE(0);
      for (int u = 0; u < nt_; u += 2) {
        asm volatile("s_waitcnt lgkmcnt(0)" ::: "memory");
        __builtin_amdgcn_s_barrier();
        if (u + 1 < nt_) {
          STAGE(1);
          asm volatile("s_waitcnt vmcnt(4)" ::: "memory");
        } else {
          asm volatile("s_waitcnt vmcnt(0)" ::: "memory");
        }
        TILE_COMPUTE(u, 0);
        if (u + 1 >= nt_) break;
        asm volatile("s_waitcnt lgkmcnt(0)" ::: "memory");
        __builtin_amdgcn_s_barrier();
        if (u + 2 < nt_) {
          STAGE(0);
          asm volatile("s_waitcnt vmcnt(4)" ::: "memory");
        } else {
          asm volatile("s_waitcnt vmcnt(0)" ::: "memory");
        }
        TILE_COMPUTE(u + 1, 1);
      }
      float inv = 1.0f / lacc[0];
      unsigned short* yp = Y + (mrow0 + qbase_ + fr) * 1024 + h * 64 + kq * 4;
#pragma unroll
      for (int db = 0; db < 4; db++) {
        ushort4 o;
        o.x = f2bf(acc[db][0] * inv);
        o.y = f2bf(acc[db][1] * inv);
        o.z = f2bf(acc[db][2] * inv);
        o.w = f2bf(acc[db][3] * inv);
        *reinterpret_cast<ushort4*>(yp + db * 16) = o;
      }
    }
  }
#undef TILE_COMPUTE
#undef STAGE
}

// ---------- combine partials for L tiles (q-tiles 16..31) ----------
__global__ __launch_bounds__(256) void attn_combine(const unsigned short* __restrict__ Opart,
                                                    const float* __restrict__ Lsum,
                                                    unsigned short* __restrict__ Y) {
  int bid = blockIdx.x;     // 512 = 16 pairs x 32 bh
  int pair = bid >> 5;
  int bh = bid & 31;
  int Lt = 31 - pair;
  int h = bh & 15, b = bh >> 4;
  int t = threadIdx.x;
  int q = t >> 2, d0 = (t & 3) * 16;
  size_t s0 = (size_t)((pair * 2 + 0) * 32 + bh);
  size_t s1 = (size_t)((pair * 2 + 1) * 32 + bh);
  float inv = 1.0f / (Lsum[s0 * 64 + q] + Lsum[s1 * 64 + q]);
  const unsigned short* p0 = Opart + s0 * 4096;
  const unsigned short* p1 = Opart + s1 * 4096;
  bf16x8 o0, o1;
#pragma unroll
  for (int i = 0; i < 8; i++) {
    int d = d0 + i;
    o0[i] = (short)f2bf((bf2f(p0[d * 64 + q]) + bf2f(p1[d * 64 + q])) * inv);
  }
#pragma unroll
  for (int i = 0; i < 8; i++) {
    int d = d0 + 8 + i;
    o1[i] = (short)f2bf((bf2f(p0[d * 64 + q]) + bf2f(p1[d * 64 + q])) * inv);
  }
  unsigned short* yp = Y + ((size_t)(b * 2048 + Lt * 64 + q)) * 1024 + h * 64 + d0;
  *reinterpret_cast<bf16x8*>(yp) = o0;
  *reinterpret_cast<bf16x8*>(yp + 8) = o1;
}

// ---------- launch ----------
extern "C" void kernel_launch(void* const* d_in, const int* in_sizes, int n_in,
                              void* d_out, int out_size, void* d_ws, size_t ws_size,
                              hipStream_t stream) {
  const float* x     = (const float*)d_in[0];   // [2,2048,1024]
  const float* w_qkv = (const float*)d_in[1];   // [3072,1024]
  const float* w_o   = (const float*)d_in[2];   // [1024,1024]
  const int*   pos   = (const int*)d_in[3];     // [2048]
  float* out = (float*)d_out;                   // [2,2048,1024] f32

  unsigned char* ws = (unsigned char*)d_ws;
  unsigned short* x_bf    = (unsigned short*)(ws);               //  8,388,608 B
  unsigned short* wqkv_bf = (unsigned short*)(ws + 8388608);     //  6,291,456 B
  unsigned short* wo_bf   = (unsigned short*)(ws + 14680064);    //  2,097,152 B
  unsigned short* qkv     = (unsigned short*)(ws + 16777216);    // 25,165,824 B
  unsigned short* vt      = (unsigned short*)(ws + 41943040);    //  8,388,608 B
  unsigned short* y       = (unsigned short*)(ws + 50331648);    //  8,388,608 B
  // attn scratch reuses regions dead after gemm8:
  unsigned short* Opart = x_bf;                  // 8,388,608 B
  float* Lsum = (float*)wqkv_bf;                 //   262,144 B

  cvt3_f32_bf16<<<1536, 256, 0, stream>>>(x, x_bf, 4096 * 1024 / 4,
                                          w_qkv, wqkv_bf, 3072 * 1024 / 4,
                                          w_o, wo_bf, 1024 * 1024 / 4);

  gemm8_qkv<<<256, 512, 0, stream>>>(x_bf, wqkv_bf, qkv);

  rope_vtrans_kernel<<<5120, 256, 0, stream>>>(qkv, pos, vt);

  attn_kernel<<<1024, 256, 0, stream>>>(qkv, vt, y, Opart, Lsum);
  attn_combine<<<512, 256, 0, stream>>>(Opart, Lsum, y);

  gemm_wo<<<dim3(32, 16), 256, 0, stream>>>(y, wo_bf, out, 1024);
}